// Round 5
// baseline (664.510 us; speedup 1.0000x reference)
//
#include <hip/hip_runtime.h>
#include <stdint.h>
#include <stddef.h>

typedef _Float16 half_t;
typedef _Float16 half4 __attribute__((ext_vector_type(4)));
typedef _Float16 half8 __attribute__((ext_vector_type(8)));

// ---------------------------------------------------------------------------
// JAX threefry2x32 (partitionable mode — verified: absmax 2.4e-4).
// ---------------------------------------------------------------------------
__host__ __device__ __forceinline__ uint32_t rotl32(uint32_t v, uint32_t r) {
  return (v << r) | (v >> (32u - r));
}

__host__ __device__ __forceinline__ void tf2x32(uint32_t k0, uint32_t k1,
                                                uint32_t x0, uint32_t x1,
                                                uint32_t& o0, uint32_t& o1) {
  uint32_t ks2 = k0 ^ k1 ^ 0x1BD11BDAu;
  x0 += k0; x1 += k1;
  x0 += x1; x1 = rotl32(x1, 13); x1 ^= x0;
  x0 += x1; x1 = rotl32(x1, 15); x1 ^= x0;
  x0 += x1; x1 = rotl32(x1, 26); x1 ^= x0;
  x0 += x1; x1 = rotl32(x1, 6);  x1 ^= x0;
  x0 += k1; x1 += ks2 + 1u;
  x0 += x1; x1 = rotl32(x1, 17); x1 ^= x0;
  x0 += x1; x1 = rotl32(x1, 29); x1 ^= x0;
  x0 += x1; x1 = rotl32(x1, 16); x1 ^= x0;
  x0 += x1; x1 = rotl32(x1, 24); x1 ^= x0;
  x0 += ks2; x1 += k0 + 2u;
  x0 += x1; x1 = rotl32(x1, 13); x1 ^= x0;
  x0 += x1; x1 = rotl32(x1, 15); x1 ^= x0;
  x0 += x1; x1 = rotl32(x1, 26); x1 ^= x0;
  x0 += x1; x1 = rotl32(x1, 6);  x1 ^= x0;
  x0 += k0; x1 += k1 + 3u;
  x0 += x1; x1 = rotl32(x1, 17); x1 ^= x0;
  x0 += x1; x1 = rotl32(x1, 29); x1 ^= x0;
  x0 += x1; x1 = rotl32(x1, 16); x1 ^= x0;
  x0 += x1; x1 = rotl32(x1, 24); x1 ^= x0;
  x0 += k1; x1 += ks2 + 4u;
  x0 += x1; x1 = rotl32(x1, 13); x1 ^= x0;
  x0 += x1; x1 = rotl32(x1, 15); x1 ^= x0;
  x0 += x1; x1 = rotl32(x1, 26); x1 ^= x0;
  x0 += x1; x1 = rotl32(x1, 6);  x1 ^= x0;
  x0 += ks2; x1 += k0 + 5u;
  o0 = x0; o1 = x1;
}

__device__ __forceinline__ bool tf_keep(uint32_t k0, uint32_t k1, uint32_t idx) {
  uint32_t o0, o1;
  tf2x32(k0, k1, 0u, idx, o0, o1);
  return ((o0 ^ o1) >> 31) == 0u;
}

// ---------------------------------------------------------------------------
// CSR build v3: direct global-atomic histogram + two-level scan + atomic
// placement. Replaces staged k4/k3/k5 (removes staging write, scattered
// staging re-read, stash pass, per-entry binary search).
// ---------------------------------------------------------------------------
__global__ __launch_bounds__(256) void k_zero(uint32_t* __restrict__ deg, int n) {
  int i = blockIdx.x * 256 + threadIdx.x;
  int gs = gridDim.x * 256;
  for (; i < n; i += gs) deg[i] = 0u;
}

__global__ __launch_bounds__(256) void k_deg(const int* __restrict__ dst,
                                             uint32_t* __restrict__ deg, int E) {
  int i = blockIdx.x * 256 + threadIdx.x;
  int gs = gridDim.x * 256;
  for (; i < E; i += gs) {
    uint32_t d = (uint32_t)__builtin_nontemporal_load(&dst[i]);
    atomicAdd(&deg[d], 1u);
  }
}

// 1024 nodes per block: local exclusive scan of deg -> rowp (local), block
// total -> bsum, and dinv = rsqrt(deg+1) (self-loop included).
__global__ __launch_bounds__(1024) void k_scan1(const uint32_t* __restrict__ deg,
                                                uint32_t* __restrict__ rowp,
                                                uint32_t* __restrict__ bsum,
                                                float* __restrict__ dinv, int n) {
  __shared__ uint32_t ls[1024];
  int t = threadIdx.x;
  int j = blockIdx.x * 1024 + t;
  uint32_t v = (j < n) ? deg[j] : 0u;
  ls[t] = v;
  __syncthreads();
  for (int off = 1; off < 1024; off <<= 1) {
    uint32_t x = (t >= off) ? ls[t - off] : 0u;
    __syncthreads();
    if (t >= off) ls[t] += x;
    __syncthreads();
  }
  if (j < n) {
    rowp[j] = ls[t] - v;  // local exclusive
    dinv[j] = 1.0f / sqrtf((float)(v + 1u));
  }
  if (t == 1023) bsum[blockIdx.x] = ls[1023];
}

// Scan block sums (NBB <= 128).
__global__ __launch_bounds__(128) void k_scan2(const uint32_t* __restrict__ bsum,
                                               uint32_t* __restrict__ boffs, int NBB) {
  __shared__ uint32_t s[128];
  int t = threadIdx.x;
  uint32_t v = (t < NBB) ? bsum[t] : 0u;
  s[t] = v;
  __syncthreads();
  for (int off = 1; off < 128; off <<= 1) {
    uint32_t x = (t >= off) ? s[t - off] : 0u;
    __syncthreads();
    if (t >= off) s[t] += x;
    __syncthreads();
  }
  if (t < NBB) boffs[t] = s[t] - v;  // exclusive
}

// Finalize rowp to global offsets; init placement cursors.
__global__ __launch_bounds__(256) void k_scan3(uint32_t* __restrict__ rowp,
                                               const uint32_t* __restrict__ boffs,
                                               uint32_t* __restrict__ cur,
                                               int n, int E) {
  int i = blockIdx.x * 256 + threadIdx.x;
  int gs = gridDim.x * 256;
  for (; i < n; i += gs) {
    uint32_t r = rowp[i] + boffs[i >> 10];
    rowp[i] = r;
    cur[i] = r;
  }
  if (blockIdx.x == 0 && threadIdx.x == 0) rowp[n] = (uint32_t)E;
}

__global__ __launch_bounds__(256) void k_place(const int* __restrict__ src,
                                               const int* __restrict__ dst,
                                               uint32_t* __restrict__ cur,
                                               uint32_t* __restrict__ esrc, int E) {
  int i = blockIdx.x * 256 + threadIdx.x;
  int gs = gridDim.x * 256;
  for (; i < E; i += gs) {
    uint32_t s = (uint32_t)__builtin_nontemporal_load(&src[i]);
    uint32_t d = (uint32_t)__builtin_nontemporal_load(&dst[i]);
    uint32_t pos = atomicAdd(&cur[d], 1u);
    esrc[pos] = s;
  }
}

// ---------------------------------------------------------------------------
// GEMM: out16[n,32] = fp16( dinv[row] * (X[n,64] @ W[64,32]) )  (row-major).
// ---------------------------------------------------------------------------
__global__ __launch_bounds__(256) void gemm_n64_k32(
    const float* __restrict__ X, const float* __restrict__ W,
    const float* __restrict__ dinv, half_t* __restrict__ out16, int n) {
  __shared__ float Ws[64 * 32];
  __shared__ float Xs[32 * 68];
  int tid = threadIdx.x;
  {
    const float4* Wv = (const float4*)W;
    float4* Wsv = (float4*)Ws;
    Wsv[tid] = Wv[tid];
    Wsv[tid + 256] = Wv[tid + 256];
  }
  int row0 = blockIdx.x * 32;
  {
    const float4* Xv = (const float4*)(X + (size_t)row0 * 64);
    int lim = (n - row0) * 16;
    float4 z = make_float4(0.f, 0.f, 0.f, 0.f);
    int i0 = tid, i1 = tid + 256;
    float4 v0 = (i0 < lim) ? Xv[i0] : z;
    float4 v1 = (i1 < lim) ? Xv[i1] : z;
    *(float4*)(Xs + (i0 >> 4) * 68 + ((i0 & 15) << 2)) = v0;
    *(float4*)(Xs + (i1 >> 4) * 68 + ((i1 & 15) << 2)) = v1;
  }
  __syncthreads();
  int r = tid >> 3;
  int c4 = (tid & 7) << 2;
  int row = row0 + r;
  if (row >= n) return;
  float4 acc = make_float4(0.f, 0.f, 0.f, 0.f);
#pragma unroll
  for (int k = 0; k < 64; k += 4) {
    float4 xv = *(const float4*)(Xs + r * 68 + k);
    float4 w0 = *(const float4*)(Ws + (k + 0) * 32 + c4);
    float4 w1 = *(const float4*)(Ws + (k + 1) * 32 + c4);
    float4 w2 = *(const float4*)(Ws + (k + 2) * 32 + c4);
    float4 w3 = *(const float4*)(Ws + (k + 3) * 32 + c4);
    acc.x = fmaf(xv.x, w0.x, acc.x); acc.y = fmaf(xv.x, w0.y, acc.y);
    acc.z = fmaf(xv.x, w0.z, acc.z); acc.w = fmaf(xv.x, w0.w, acc.w);
    acc.x = fmaf(xv.y, w1.x, acc.x); acc.y = fmaf(xv.y, w1.y, acc.y);
    acc.z = fmaf(xv.y, w1.z, acc.z); acc.w = fmaf(xv.y, w1.w, acc.w);
    acc.x = fmaf(xv.z, w2.x, acc.x); acc.y = fmaf(xv.z, w2.y, acc.y);
    acc.z = fmaf(xv.z, w2.z, acc.z); acc.w = fmaf(xv.z, w2.w, acc.w);
    acc.x = fmaf(xv.w, w3.x, acc.x); acc.y = fmaf(xv.w, w3.y, acc.y);
    acc.z = fmaf(xv.w, w3.z, acc.z); acc.w = fmaf(xv.w, w3.w, acc.w);
  }
  float dj = dinv[row];
  half4 h;
  h.x = (half_t)(acc.x * dj); h.y = (half_t)(acc.y * dj);
  h.z = (half_t)(acc.z * dj); h.w = (half_t)(acc.w * dj);
  *(half4*)(out16 + (size_t)row * 32 + c4) = h;
}

// ---------------------------------------------------------------------------
// GEMM: out[n,64] = dropout(celu(X[n,32] @ W[32,64] + b))  (fp32 in/out).
// ---------------------------------------------------------------------------
__global__ __launch_bounds__(256) void gemm_k32_n64_act(
    const float* __restrict__ X, const float* __restrict__ W,
    const float* __restrict__ bias, float* __restrict__ out,
    uint32_t k0, uint32_t k1, int n) {
  __shared__ float Ws[32 * 64];
  __shared__ float Xs[16 * 36];
  int tid = threadIdx.x;
  {
    const float4* Wv = (const float4*)W;
    float4* Wsv = (float4*)Ws;
    Wsv[tid] = Wv[tid];
    Wsv[tid + 256] = Wv[tid + 256];
  }
  int row0 = blockIdx.x * 16;
  if (tid < 128) {
    const float4* Xv = (const float4*)(X + (size_t)row0 * 32);
    int lim = (n - row0) * 8;
    float4 z = make_float4(0.f, 0.f, 0.f, 0.f);
    float4 v = (tid < lim) ? Xv[tid] : z;
    *(float4*)(Xs + (tid >> 3) * 36 + ((tid & 7) << 2)) = v;
  }
  __syncthreads();
  int r = tid >> 4;
  int c4 = (tid & 15) << 2;
  int row = row0 + r;
  if (row >= n) return;
  float4 acc = make_float4(0.f, 0.f, 0.f, 0.f);
#pragma unroll
  for (int k = 0; k < 32; k += 4) {
    float4 xv = *(const float4*)(Xs + r * 36 + k);
    float4 w0 = *(const float4*)(Ws + (k + 0) * 64 + c4);
    float4 w1 = *(const float4*)(Ws + (k + 1) * 64 + c4);
    float4 w2 = *(const float4*)(Ws + (k + 2) * 64 + c4);
    float4 w3 = *(const float4*)(Ws + (k + 3) * 64 + c4);
    acc.x = fmaf(xv.x, w0.x, acc.x); acc.y = fmaf(xv.x, w0.y, acc.y);
    acc.z = fmaf(xv.x, w0.z, acc.z); acc.w = fmaf(xv.x, w0.w, acc.w);
    acc.x = fmaf(xv.y, w1.x, acc.x); acc.y = fmaf(xv.y, w1.y, acc.y);
    acc.z = fmaf(xv.y, w1.z, acc.z); acc.w = fmaf(xv.y, w1.w, acc.w);
    acc.x = fmaf(xv.z, w2.x, acc.x); acc.y = fmaf(xv.z, w2.y, acc.y);
    acc.z = fmaf(xv.z, w2.z, acc.z); acc.w = fmaf(xv.z, w2.w, acc.w);
    acc.x = fmaf(xv.w, w3.x, acc.x); acc.y = fmaf(xv.w, w3.y, acc.y);
    acc.z = fmaf(xv.w, w3.z, acc.z); acc.w = fmaf(xv.w, w3.w, acc.w);
  }
  float4 bv = *(const float4*)(bias + c4);
  float vv[4] = {acc.x + bv.x, acc.y + bv.y, acc.z + bv.z, acc.w + bv.w};
  uint32_t base = (uint32_t)row * 64u + (uint32_t)c4;
#pragma unroll
  for (int q = 0; q < 4; ++q) {
    float v = vv[q];
    v = v > 0.f ? v : expm1f(v);
    vv[q] = tf_keep(k0, k1, base + q) ? v * 2.f : 0.f;
  }
  *(float4*)(out + (size_t)row * 64 + c4) = make_float4(vv[0], vv[1], vv[2], vv[3]);
}

// ---------------------------------------------------------------------------
// Gather-reduce v9 (EXACT R3 code — proven 41.7 µs): 64-edge iterations,
// 8x half8 masked loads, pairwise fp16 add, fp32 accumulate. TLP across
// 12500 small blocks provides the latency overlap (persistent/pipelined
// variants measured worse: R2 −, R4 −).
// ---------------------------------------------------------------------------
__global__ __launch_bounds__(256) void gather_fin(
    const half_t* __restrict__ hs, const uint32_t* __restrict__ rowp,
    const uint32_t* __restrict__ esrc, const float* __restrict__ dinv,
    const float* __restrict__ bias, float* __restrict__ outf,
    half_t* __restrict__ outh, int n, int mode, uint32_t k0, uint32_t k1,
    float fone) {
  __shared__ __align__(16) float ldsred[256];
  (void)fone;
  int tid = threadIdx.x;
  int gt = blockIdx.x * 256 + tid;
  int j = gt >> 5;
  int g = tid >> 5;
  int l = tid & 31;
  int eslot = l >> 2;
  int chunk = l & 3;
  float acc[8] = {0.f, 0.f, 0.f, 0.f, 0.f, 0.f, 0.f, 0.f};
  uint32_t e0 = 0, deg = 0;
  float selfv = 0.f, dj = 0.f;
  if (j < n) {
    e0 = rowp[j];
    deg = rowp[j + 1] - e0;
    selfv = (float)hs[(size_t)j * 32 + l];  // hoisted: independent of loop
    dj = dinv[j];
  }
  const half_t* hp = hs + (size_t)(chunk << 3);
  const half8 hz = {(half_t)0, (half_t)0, (half_t)0, (half_t)0,
                    (half_t)0, (half_t)0, (half_t)0, (half_t)0};
  for (uint32_t base = 0; base < deg; base += 64u) {
    uint32_t rem = deg - base;
    if (rem > 64u) rem = 64u;
    uint32_t li0 = (uint32_t)l < rem ? (uint32_t)l : rem - 1u;
    uint32_t t1 = 32u + (uint32_t)l;
    uint32_t li1 = t1 < rem ? t1 : rem - 1u;
    uint32_t idx0 = __builtin_nontemporal_load(&esrc[e0 + base + li0]);
    uint32_t idx1 = __builtin_nontemporal_load(&esrc[e0 + base + li1]);
    half8 v0, v1, v2, v3, v4, v5, v6, v7;
#define GLOAD(KK, IDX, VOUT)                                              \
    {                                                                     \
      uint32_t kp = (uint32_t)(KK) + (uint32_t)eslot;                     \
      uint32_t s = (uint32_t)__shfl((int)(IDX), (int)(kp & 31u), 32);     \
      VOUT = hz;                                                          \
      if (kp < rem) VOUT = *(const half8*)(hp + ((size_t)s << 5));        \
    }
    GLOAD(0,  idx0, v0)
    GLOAD(8,  idx0, v1)
    GLOAD(16, idx0, v2)
    GLOAD(24, idx0, v3)
    GLOAD(32, idx1, v4)
    GLOAD(40, idx1, v5)
    GLOAD(48, idx1, v6)
    GLOAD(56, idx1, v7)
#undef GLOAD
    half8 s01 = v0 + v1;
    half8 s23 = v2 + v3;
    half8 s45 = v4 + v5;
    half8 s67 = v6 + v7;
#pragma unroll
    for (int q = 0; q < 8; ++q) {
      acc[q] += (float)s01[q];
      acc[q] += (float)s23[q];
      acc[q] += (float)s45[q];
      acc[q] += (float)s67[q];
    }
  }
#pragma unroll
  for (int m = 4; m <= 16; m <<= 1) {
#pragma unroll
    for (int q = 0; q < 8; ++q) acc[q] += __shfl_xor(acc[q], m);
  }
  if (l < 4) {
    *(float4*)(&ldsred[(g << 5) + (chunk << 3) + 0]) =
        make_float4(acc[0], acc[1], acc[2], acc[3]);
    *(float4*)(&ldsred[(g << 5) + (chunk << 3) + 4]) =
        make_float4(acc[4], acc[5], acc[6], acc[7]);
  }
  __builtin_amdgcn_wave_barrier();
  if (j >= n) return;
  float sum = ldsred[(g << 5) + l];
  sum += selfv;
  float v = dj * sum;
  if (mode == 1) {
    v += bias[l];
    v = v > 0.f ? v : expm1f(v);
    __builtin_nontemporal_store(v, &outf[gt]);
  } else if (mode == 3) {
    v += bias[l];
    v = v > 0.f ? v : expm1f(v);
    v = tf_keep(k0, k1, (uint32_t)gt) ? v * 2.f : 0.f;
    v *= dj;
    __builtin_nontemporal_store((half_t)v, &outh[gt]);
  } else {
    __builtin_nontemporal_store(v, &outf[gt]);
  }
}

// ---------------------------------------------------------------------------
extern "C" void kernel_launch(void* const* d_in, const int* in_sizes, int n_in,
                              void* d_out, int out_size, void* d_ws, size_t ws_size,
                              hipStream_t stream) {
  const float* x  = (const float*)d_in[0];
  const int*   ei = (const int*)d_in[1];
  const float* W1 = (const float*)d_in[2];
  const float* b1 = (const float*)d_in[3];
  const float* W2 = (const float*)d_in[4];
  const float* b2 = (const float*)d_in[5];
  const float* W3 = (const float*)d_in[6];
  const float* b3 = (const float*)d_in[7];
  float* out = (float*)d_out;

  const int n = in_sizes[0] / 64;
  const int E = in_sizes[1] / 2;
  const int* src = ei;
  const int* dst = ei + E;

  char* ws = (char*)d_ws;
  size_t off = 0;
  auto alloc = [&](size_t bytes) {
    void* p = ws + off;
    off = (off + bytes + 255) & ~(size_t)255;
    return p;
  };
  float*    A32   = (float*)alloc((size_t)n * 32 * 4);  // gather2 out / gemm2 in
  float*    C     = (float*)alloc((size_t)n * 64 * 4);  // gemm2 out
  half_t*   A16   = (half_t*)alloc((size_t)n * 32 * 2); // fp16 row-major table
  half_t*   B16   = (half_t*)alloc((size_t)n * 32 * 2); // fp16 row-major table
  float*    dinv  = (float*)alloc((size_t)n * 4);
  uint32_t* rowp  = (uint32_t*)alloc((size_t)(n + 1) * 4);
  uint32_t* esrc  = (uint32_t*)alloc((size_t)E * 4);
  uint32_t* deg   = (uint32_t*)alloc((size_t)n * 4);
  uint32_t* cur   = (uint32_t*)alloc((size_t)n * 4);
  uint32_t* bsum  = (uint32_t*)alloc(1024 * 4);
  uint32_t* boffs = (uint32_t*)alloc(1024 * 4);
  (void)ws_size; (void)n_in; (void)out_size;

  uint32_t k1a, k1b, k2a, k2b;
  tf2x32(0u, 42u, 0u, 0u, k1a, k1b);
  tf2x32(0u, 42u, 0u, 1u, k2a, k2b);

  const int NBB  = (n + 1023) >> 10;      // scan blocks (<=128 for n<=131072)
  const int nv   = n * 32;
  const int gV   = (nv + 255) / 256;
  const int gG1  = (n + 31) / 32;
  const int gG2  = (n + 15) / 16;
  const int gN   = (n + 255) / 256;
  dim3 blk(256);

  // ---- CSR build v3: atomic histogram + scan + atomic placement ----
  k_zero<<<gN, blk, 0, stream>>>(deg, n);
  k_deg<<<2048, blk, 0, stream>>>(dst, deg, E);
  k_scan1<<<NBB, dim3(1024), 0, stream>>>(deg, rowp, bsum, dinv, n);
  k_scan2<<<1, dim3(128), 0, stream>>>(bsum, boffs, NBB);
  k_scan3<<<gN, blk, 0, stream>>>(rowp, boffs, cur, n, E);
  k_place<<<2048, blk, 0, stream>>>(src, dst, cur, esrc, E);

  // ---- layer 1: A16 = fp16(dinv*(x@W1)); gather -> B16 (fp16) ----
  gemm_n64_k32<<<gG1, blk, 0, stream>>>(x, W1, dinv, A16, n);
  gather_fin<<<gV, blk, 0, stream>>>(A16, rowp, esrc, dinv, b1, nullptr, B16, n, 3, k1a, k1b, 1.0f);

  // ---- layer 2: gather(B16) -> A32 (fp32); gemm2 -> C ----
  gather_fin<<<gV, blk, 0, stream>>>(B16, rowp, esrc, dinv, nullptr, A32, nullptr, n, 0, 0u, 0u, 1.0f);
  gemm_k32_n64_act<<<gG2, blk, 0, stream>>>(A32, W2, b2, C, k2a, k2b, n);

  // ---- layer 3: A16 = fp16(dinv*(C@W3)); gather -> out (fp32) ----
  gemm_n64_k32<<<gG1, blk, 0, stream>>>(C, W3, dinv, A16, n);
  gather_fin<<<gV, blk, 0, stream>>>(A16, rowp, esrc, dinv, b3, out, nullptr, n, 1, 0u, 0u, 1.0f);
}

// Round 6
// 312.468 us; speedup vs baseline: 2.1266x; 2.1266x over previous
//
#include <hip/hip_runtime.h>
#include <stdint.h>
#include <stddef.h>

typedef _Float16 half_t;
typedef _Float16 half4 __attribute__((ext_vector_type(4)));
typedef _Float16 half8 __attribute__((ext_vector_type(8)));

// ---------------------------------------------------------------------------
// JAX threefry2x32 (partitionable mode — verified: absmax 2.4e-4).
// ---------------------------------------------------------------------------
__host__ __device__ __forceinline__ uint32_t rotl32(uint32_t v, uint32_t r) {
  return (v << r) | (v >> (32u - r));
}

__host__ __device__ __forceinline__ void tf2x32(uint32_t k0, uint32_t k1,
                                                uint32_t x0, uint32_t x1,
                                                uint32_t& o0, uint32_t& o1) {
  uint32_t ks2 = k0 ^ k1 ^ 0x1BD11BDAu;
  x0 += k0; x1 += k1;
  x0 += x1; x1 = rotl32(x1, 13); x1 ^= x0;
  x0 += x1; x1 = rotl32(x1, 15); x1 ^= x0;
  x0 += x1; x1 = rotl32(x1, 26); x1 ^= x0;
  x0 += x1; x1 = rotl32(x1, 6);  x1 ^= x0;
  x0 += k1; x1 += ks2 + 1u;
  x0 += x1; x1 = rotl32(x1, 17); x1 ^= x0;
  x0 += x1; x1 = rotl32(x1, 29); x1 ^= x0;
  x0 += x1; x1 = rotl32(x1, 16); x1 ^= x0;
  x0 += x1; x1 = rotl32(x1, 24); x1 ^= x0;
  x0 += ks2; x1 += k0 + 2u;
  x0 += x1; x1 = rotl32(x1, 13); x1 ^= x0;
  x0 += x1; x1 = rotl32(x1, 15); x1 ^= x0;
  x0 += x1; x1 = rotl32(x1, 26); x1 ^= x0;
  x0 += x1; x1 = rotl32(x1, 6);  x1 ^= x0;
  x0 += k0; x1 += k1 + 3u;
  x0 += x1; x1 = rotl32(x1, 17); x1 ^= x0;
  x0 += x1; x1 = rotl32(x1, 29); x1 ^= x0;
  x0 += x1; x1 = rotl32(x1, 16); x1 ^= x0;
  x0 += x1; x1 = rotl32(x1, 24); x1 ^= x0;
  x0 += k1; x1 += ks2 + 4u;
  x0 += x1; x1 = rotl32(x1, 13); x1 ^= x0;
  x0 += x1; x1 = rotl32(x1, 15); x1 ^= x0;
  x0 += x1; x1 = rotl32(x1, 26); x1 ^= x0;
  x0 += x1; x1 = rotl32(x1, 6);  x1 ^= x0;
  x0 += ks2; x1 += k0 + 5u;
  o0 = x0; o1 = x1;
}

__device__ __forceinline__ bool tf_keep(uint32_t k0, uint32_t k1, uint32_t idx) {
  uint32_t o0, o1;
  tf2x32(k0, k1, 0u, idx, o0, o1);
  return ((o0 ^ o1) >> 31) == 0u;
}

// ---------------------------------------------------------------------------
// CSR build (R3-proven): chunk-histogram k4 (1024 thr) + scan + k5 staged
// placement. R5's global-atomic variant measured 290 µs in k_place alone —
// scattered fetch-add atomics are fabric-latency-bound; do not revisit.
// ---------------------------------------------------------------------------
#define CHUNK 4096
#define STASH 5120

__global__ __launch_bounds__(1024) void zero1024(uint32_t* __restrict__ p) {
  p[threadIdx.x] = 0u;
}

__global__ __launch_bounds__(1024) void k4_binhist(const int* __restrict__ src,
                                                   const int* __restrict__ dst,
                                                   uint32_t* __restrict__ tbl,
                                                   uint32_t* __restrict__ gbcnt,
                                                   uint32_t* __restrict__ staging,
                                                   int E, int NB) {
  __shared__ uint32_t lcur[1024];
  __shared__ uint32_t ls[1024];
  __shared__ uint32_t stage[CHUNK];
  int tid = threadIdx.x;
  lcur[tid] = 0u;
  __syncthreads();
  int base = blockIdx.x * CHUNK;
  int end = min(base + CHUNK, E);
  uint32_t dv[4], sv[4];
  int m = 0;
  for (int i = base + tid; i < end; i += 1024) {
    dv[m] = (uint32_t)dst[i];
    sv[m] = (uint32_t)src[i];
    ++m;
  }
  for (int q = 0; q < m; ++q) atomicAdd(&lcur[dv[q] >> 7], 1u);
  __syncthreads();
  uint32_t v = lcur[tid];  // bins >= NB stay zero
  ls[tid] = v;
  __syncthreads();
  for (int off = 1; off < 1024; off <<= 1) {
    uint32_t t = (tid >= off) ? ls[tid - off] : 0u;
    __syncthreads();
    if (tid >= off) ls[tid] += t;
    __syncthreads();
  }
  uint32_t excl = ls[tid] - v;
  if (tid < NB) {
    tbl[(size_t)blockIdx.x * NB + tid] = (excl << 16) | v;
    if (v) atomicAdd(&gbcnt[tid], v);
  }
  lcur[tid] = excl;
  __syncthreads();
  for (int q = 0; q < m; ++q) {
    uint32_t d = dv[q];
    uint32_t p = atomicAdd(&lcur[d >> 7], 1u);
    stage[p] = ((d & 127u) << 17) | sv[q];
  }
  __syncthreads();
  int cnt_total = end - base;
  uint32_t* outp = staging + (size_t)blockIdx.x * CHUNK;
  for (int i = tid; i < cnt_total; i += 1024) outp[i] = stage[i];
}

__global__ __launch_bounds__(1024) void k3_bscan(const uint32_t* __restrict__ gbcnt,
                                                 uint32_t* __restrict__ bbase, int NB) {
  __shared__ uint32_t s[1024];
  int i = threadIdx.x;
  uint32_t v = (i < NB) ? gbcnt[i] : 0u;
  s[i] = v;
  __syncthreads();
  for (int off = 1; off < 1024; off <<= 1) {
    uint32_t t = (i >= off) ? s[i - off] : 0u;
    __syncthreads();
    if (i >= off) s[i] += t;
    __syncthreads();
  }
  if (i < NB) bbase[i] = s[i] - v;
}

__global__ __launch_bounds__(1024) void k5_fin(
    const uint32_t* __restrict__ staging, const uint32_t* __restrict__ tbl,
    const uint32_t* __restrict__ bbase, uint32_t* __restrict__ rowp,
    float* __restrict__ dinv, uint32_t* __restrict__ esrc,
    int n, int E, int NBLK, int NB) {
  __shared__ uint32_t loff[1024];
  __shared__ uint32_t P[1025];
  __shared__ uint32_t ls[1024];
  __shared__ uint32_t stash[STASH];
  __shared__ uint32_t lc[128];
  __shared__ uint32_t sc[128];
  __shared__ uint32_t lcur[128];
  int tid = threadIdx.x;
  int b = blockIdx.x;
  if (tid < 128) lc[tid] = 0u;
  uint32_t packed = (tid < NBLK) ? tbl[(size_t)tid * NB + b] : 0u;
  uint32_t v = packed & 0xFFFFu;
  loff[tid] = packed >> 16;
  ls[tid] = v;
  __syncthreads();
  for (int off = 1; off < 1024; off <<= 1) {
    uint32_t t = (tid >= off) ? ls[tid - off] : 0u;
    __syncthreads();
    if (tid >= off) ls[tid] += t;
    __syncthreads();
  }
  P[tid] = ls[tid] - v;
  if (tid == 1023) P[1024] = ls[1023];
  __syncthreads();
  uint32_t total = P[NBLK];
  for (uint32_t q = (uint32_t)tid; q < total; q += 1024u) {
    int lo = 0, hi = NBLK;
    while (hi - lo > 1) {
      int mid = (lo + hi) >> 1;
      if (P[mid] <= q) lo = mid; else hi = mid;
    }
    uint32_t e = staging[(size_t)lo * CHUNK + loff[lo] + (q - P[lo])];
    if (q < (uint32_t)STASH) stash[q] = e;
    atomicAdd(&lc[e >> 17], 1u);
  }
  __syncthreads();
  uint32_t myc = (tid < 128) ? lc[tid] : 0u;
  if (tid < 128) sc[tid] = myc;
  __syncthreads();
  for (int off = 1; off < 128; off <<= 1) {
    uint32_t t = (tid < 128 && tid >= off) ? sc[tid - off] : 0u;
    __syncthreads();
    if (tid < 128 && tid >= off) sc[tid] += t;
    __syncthreads();
  }
  uint32_t s = bbase[b];
  if (tid < 128) {
    uint32_t gstart = s + sc[tid] - myc;
    int node = (b << 7) + tid;
    if (node < n) {
      rowp[node] = gstart;
      dinv[node] = 1.0f / sqrtf((float)(myc + 1u));
    }
    lcur[tid] = gstart;
  }
  if (b == 0 && tid == 0) rowp[n] = (uint32_t)E;
  __syncthreads();
  uint32_t lim = total < (uint32_t)STASH ? total : (uint32_t)STASH;
  for (uint32_t q = (uint32_t)tid; q < lim; q += 1024u) {
    uint32_t e = stash[q];
    uint32_t pos = atomicAdd(&lcur[e >> 17], 1u);
    esrc[pos] = e & 0x1FFFFu;
  }
  if (total > (uint32_t)STASH) {
    for (uint32_t q = (uint32_t)STASH + (uint32_t)tid; q < total; q += 1024u) {
      int lo = 0, hi = NBLK;
      while (hi - lo > 1) {
        int mid = (lo + hi) >> 1;
        if (P[mid] <= q) lo = mid; else hi = mid;
      }
      uint32_t e = staging[(size_t)lo * CHUNK + loff[lo] + (q - P[lo])];
      uint32_t pos = atomicAdd(&lcur[e >> 17], 1u);
      esrc[pos] = e & 0x1FFFFu;
    }
  }
}

// ---------------------------------------------------------------------------
// GEMM: out16[n,32] = fp16( dinv[row] * (X[n,64] @ W[64,32]) )  (row-major).
// Used for layer 1 only (layer-3 instance is fused into gather_gemm2).
// ---------------------------------------------------------------------------
__global__ __launch_bounds__(256) void gemm_n64_k32(
    const float* __restrict__ X, const float* __restrict__ W,
    const float* __restrict__ dinv, half_t* __restrict__ out16, int n) {
  __shared__ float Ws[64 * 32];
  __shared__ float Xs[32 * 68];
  int tid = threadIdx.x;
  {
    const float4* Wv = (const float4*)W;
    float4* Wsv = (float4*)Ws;
    Wsv[tid] = Wv[tid];
    Wsv[tid + 256] = Wv[tid + 256];
  }
  int row0 = blockIdx.x * 32;
  {
    const float4* Xv = (const float4*)(X + (size_t)row0 * 64);
    int lim = (n - row0) * 16;
    float4 z = make_float4(0.f, 0.f, 0.f, 0.f);
    int i0 = tid, i1 = tid + 256;
    float4 v0 = (i0 < lim) ? Xv[i0] : z;
    float4 v1 = (i1 < lim) ? Xv[i1] : z;
    *(float4*)(Xs + (i0 >> 4) * 68 + ((i0 & 15) << 2)) = v0;
    *(float4*)(Xs + (i1 >> 4) * 68 + ((i1 & 15) << 2)) = v1;
  }
  __syncthreads();
  int r = tid >> 3;
  int c4 = (tid & 7) << 2;
  int row = row0 + r;
  if (row >= n) return;
  float4 acc = make_float4(0.f, 0.f, 0.f, 0.f);
#pragma unroll
  for (int k = 0; k < 64; k += 4) {
    float4 xv = *(const float4*)(Xs + r * 68 + k);
    float4 w0 = *(const float4*)(Ws + (k + 0) * 32 + c4);
    float4 w1 = *(const float4*)(Ws + (k + 1) * 32 + c4);
    float4 w2 = *(const float4*)(Ws + (k + 2) * 32 + c4);
    float4 w3 = *(const float4*)(Ws + (k + 3) * 32 + c4);
    acc.x = fmaf(xv.x, w0.x, acc.x); acc.y = fmaf(xv.x, w0.y, acc.y);
    acc.z = fmaf(xv.x, w0.z, acc.z); acc.w = fmaf(xv.x, w0.w, acc.w);
    acc.x = fmaf(xv.y, w1.x, acc.x); acc.y = fmaf(xv.y, w1.y, acc.y);
    acc.z = fmaf(xv.y, w1.z, acc.z); acc.w = fmaf(xv.y, w1.w, acc.w);
    acc.x = fmaf(xv.z, w2.x, acc.x); acc.y = fmaf(xv.z, w2.y, acc.y);
    acc.z = fmaf(xv.z, w2.z, acc.z); acc.w = fmaf(xv.z, w2.w, acc.w);
    acc.x = fmaf(xv.w, w3.x, acc.x); acc.y = fmaf(xv.w, w3.y, acc.y);
    acc.z = fmaf(xv.w, w3.z, acc.z); acc.w = fmaf(xv.w, w3.w, acc.w);
  }
  float dj = dinv[row];
  half4 h;
  h.x = (half_t)(acc.x * dj); h.y = (half_t)(acc.y * dj);
  h.z = (half_t)(acc.z * dj); h.w = (half_t)(acc.w * dj);
  *(half4*)(out16 + (size_t)row * 32 + c4) = h;
}

// ---------------------------------------------------------------------------
// Gather-reduce v9 (EXACT R3 code — proven 41.7 µs). Layers 1 and 3.
// ---------------------------------------------------------------------------
__global__ __launch_bounds__(256) void gather_fin(
    const half_t* __restrict__ hs, const uint32_t* __restrict__ rowp,
    const uint32_t* __restrict__ esrc, const float* __restrict__ dinv,
    const float* __restrict__ bias, float* __restrict__ outf,
    half_t* __restrict__ outh, int n, int mode, uint32_t k0, uint32_t k1,
    float fone) {
  __shared__ __align__(16) float ldsred[256];
  (void)fone;
  int tid = threadIdx.x;
  int gt = blockIdx.x * 256 + tid;
  int j = gt >> 5;
  int g = tid >> 5;
  int l = tid & 31;
  int eslot = l >> 2;
  int chunk = l & 3;
  float acc[8] = {0.f, 0.f, 0.f, 0.f, 0.f, 0.f, 0.f, 0.f};
  uint32_t e0 = 0, deg = 0;
  float selfv = 0.f, dj = 0.f;
  if (j < n) {
    e0 = rowp[j];
    deg = rowp[j + 1] - e0;
    selfv = (float)hs[(size_t)j * 32 + l];
    dj = dinv[j];
  }
  const half_t* hp = hs + (size_t)(chunk << 3);
  const half8 hz = {(half_t)0, (half_t)0, (half_t)0, (half_t)0,
                    (half_t)0, (half_t)0, (half_t)0, (half_t)0};
  for (uint32_t base = 0; base < deg; base += 64u) {
    uint32_t rem = deg - base;
    if (rem > 64u) rem = 64u;
    uint32_t li0 = (uint32_t)l < rem ? (uint32_t)l : rem - 1u;
    uint32_t t1 = 32u + (uint32_t)l;
    uint32_t li1 = t1 < rem ? t1 : rem - 1u;
    uint32_t idx0 = __builtin_nontemporal_load(&esrc[e0 + base + li0]);
    uint32_t idx1 = __builtin_nontemporal_load(&esrc[e0 + base + li1]);
    half8 v0, v1, v2, v3, v4, v5, v6, v7;
#define GLOAD(KK, IDX, VOUT)                                              \
    {                                                                     \
      uint32_t kp = (uint32_t)(KK) + (uint32_t)eslot;                     \
      uint32_t s = (uint32_t)__shfl((int)(IDX), (int)(kp & 31u), 32);     \
      VOUT = hz;                                                          \
      if (kp < rem) VOUT = *(const half8*)(hp + ((size_t)s << 5));        \
    }
    GLOAD(0,  idx0, v0)
    GLOAD(8,  idx0, v1)
    GLOAD(16, idx0, v2)
    GLOAD(24, idx0, v3)
    GLOAD(32, idx1, v4)
    GLOAD(40, idx1, v5)
    GLOAD(48, idx1, v6)
    GLOAD(56, idx1, v7)
#undef GLOAD
    half8 s01 = v0 + v1;
    half8 s23 = v2 + v3;
    half8 s45 = v4 + v5;
    half8 s67 = v6 + v7;
#pragma unroll
    for (int q = 0; q < 8; ++q) {
      acc[q] += (float)s01[q];
      acc[q] += (float)s23[q];
      acc[q] += (float)s45[q];
      acc[q] += (float)s67[q];
    }
  }
#pragma unroll
  for (int m = 4; m <= 16; m <<= 1) {
#pragma unroll
    for (int q = 0; q < 8; ++q) acc[q] += __shfl_xor(acc[q], m);
  }
  if (l < 4) {
    *(float4*)(&ldsred[(g << 5) + (chunk << 3) + 0]) =
        make_float4(acc[0], acc[1], acc[2], acc[3]);
    *(float4*)(&ldsred[(g << 5) + (chunk << 3) + 4]) =
        make_float4(acc[4], acc[5], acc[6], acc[7]);
  }
  __builtin_amdgcn_wave_barrier();
  if (j >= n) return;
  float sum = ldsred[(g << 5) + l];
  sum += selfv;
  float v = dj * sum;
  if (mode == 1) {
    v += bias[l];
    v = v > 0.f ? v : expm1f(v);
    __builtin_nontemporal_store(v, &outf[gt]);
  } else if (mode == 3) {
    v += bias[l];
    v = v > 0.f ? v : expm1f(v);
    v = tf_keep(k0, k1, (uint32_t)gt) ? v * 2.f : 0.f;
    v *= dj;
    __builtin_nontemporal_store((half_t)v, &outh[gt]);
  } else {
    __builtin_nontemporal_store(v, &outf[gt]);
  }
}

// ---------------------------------------------------------------------------
// gather_gemm2: fused layer-2 gather + (h@W2+b2 -> celu -> dropout) +
// (t@W3 -> x dinv -> fp16 table for layer 3). The post-gather chain is
// per-node pointwise VALU (~128 FMA + 2 threefry per lane) hidden under the
// gather's memory wait. Arithmetic order matches the unfused kernels
// (ascending-k fp32 accumulation; RNG index j*64+c) so results are identical.
// ---------------------------------------------------------------------------
__global__ __launch_bounds__(256) void gather_gemm2(
    const half_t* __restrict__ hs, const uint32_t* __restrict__ rowp,
    const uint32_t* __restrict__ esrc, const float* __restrict__ dinv,
    const float* __restrict__ W2, const float* __restrict__ b2,
    const float* __restrict__ W3, half_t* __restrict__ outh,
    int n, uint32_t k0, uint32_t k1) {
  __shared__ __align__(16) float ldsred[256];
  __shared__ __align__(16) float W2s[32 * 64];
  __shared__ __align__(16) float W3s[64 * 32];
  __shared__ __align__(16) float b2s[64];
  __shared__ __align__(16) float tls[8 * 64];
  int tid = threadIdx.x;
  {
    const float4* w2v = (const float4*)W2;
    const float4* w3v = (const float4*)W3;
    float4* s2 = (float4*)W2s;
    float4* s3 = (float4*)W3s;
    s2[tid] = w2v[tid];
    s2[tid + 256] = w2v[tid + 256];
    s3[tid] = w3v[tid];
    s3[tid + 256] = w3v[tid + 256];
    if (tid < 16) ((float4*)b2s)[tid] = ((const float4*)b2)[tid];
  }
  __syncthreads();
  int j = blockIdx.x * 8 + (tid >> 5);
  int g = tid >> 5;
  int l = tid & 31;
  int eslot = l >> 2;
  int chunk = l & 3;
  float acc[8] = {0.f, 0.f, 0.f, 0.f, 0.f, 0.f, 0.f, 0.f};
  uint32_t e0 = 0, deg = 0;
  float selfv = 0.f, dj = 0.f;
  if (j < n) {
    e0 = rowp[j];
    deg = rowp[j + 1] - e0;
    selfv = (float)hs[(size_t)j * 32 + l];
    dj = dinv[j];
  }
  const half_t* hp = hs + (size_t)(chunk << 3);
  const half8 hz = {(half_t)0, (half_t)0, (half_t)0, (half_t)0,
                    (half_t)0, (half_t)0, (half_t)0, (half_t)0};
  for (uint32_t base = 0; base < deg; base += 64u) {
    uint32_t rem = deg - base;
    if (rem > 64u) rem = 64u;
    uint32_t li0 = (uint32_t)l < rem ? (uint32_t)l : rem - 1u;
    uint32_t t1 = 32u + (uint32_t)l;
    uint32_t li1 = t1 < rem ? t1 : rem - 1u;
    uint32_t idx0 = __builtin_nontemporal_load(&esrc[e0 + base + li0]);
    uint32_t idx1 = __builtin_nontemporal_load(&esrc[e0 + base + li1]);
    half8 v0, v1, v2, v3, v4, v5, v6, v7;
#define GLOAD(KK, IDX, VOUT)                                              \
    {                                                                     \
      uint32_t kp = (uint32_t)(KK) + (uint32_t)eslot;                     \
      uint32_t s = (uint32_t)__shfl((int)(IDX), (int)(kp & 31u), 32);     \
      VOUT = hz;                                                          \
      if (kp < rem) VOUT = *(const half8*)(hp + ((size_t)s << 5));        \
    }
    GLOAD(0,  idx0, v0)
    GLOAD(8,  idx0, v1)
    GLOAD(16, idx0, v2)
    GLOAD(24, idx0, v3)
    GLOAD(32, idx1, v4)
    GLOAD(40, idx1, v5)
    GLOAD(48, idx1, v6)
    GLOAD(56, idx1, v7)
#undef GLOAD
    half8 s01 = v0 + v1;
    half8 s23 = v2 + v3;
    half8 s45 = v4 + v5;
    half8 s67 = v6 + v7;
#pragma unroll
    for (int q = 0; q < 8; ++q) {
      acc[q] += (float)s01[q];
      acc[q] += (float)s23[q];
      acc[q] += (float)s45[q];
      acc[q] += (float)s67[q];
    }
  }
#pragma unroll
  for (int m = 4; m <= 16; m <<= 1) {
#pragma unroll
    for (int q = 0; q < 8; ++q) acc[q] += __shfl_xor(acc[q], m);
  }
  if (l < 4) {
    *(float4*)(&ldsred[(g << 5) + (chunk << 3) + 0]) =
        make_float4(acc[0], acc[1], acc[2], acc[3]);
    *(float4*)(&ldsred[(g << 5) + (chunk << 3) + 4]) =
        make_float4(acc[4], acc[5], acc[6], acc[7]);
  }
  __builtin_amdgcn_wave_barrier();
  // h[l] for this node (same value the unfused gather2 stored to A32)
  float hv = dj * (ldsred[(g << 5) + l] + selfv);
  __builtin_amdgcn_wave_barrier();
  ldsred[(g << 5) + l] = hv;  // publish h within group
  __builtin_amdgcn_wave_barrier();
  // t[c0], t[c1]: c = 2l, 2l+1 — ascending-k fp32 chain == gemm_k32_n64_act
  int c0 = l << 1;
  float t0 = 0.f, t1v = 0.f;
#pragma unroll
  for (int k = 0; k < 32; ++k) {
    float xk = ldsred[(g << 5) + k];
    t0 = fmaf(xk, W2s[k * 64 + c0], t0);
    t1v = fmaf(xk, W2s[k * 64 + c0 + 1], t1v);
  }
  t0 += b2s[c0];
  t1v += b2s[c0 + 1];
  t0 = t0 > 0.f ? t0 : expm1f(t0);
  t1v = t1v > 0.f ? t1v : expm1f(t1v);
  uint32_t ridx = (uint32_t)j * 64u + (uint32_t)c0;
  t0 = tf_keep(k0, k1, ridx) ? t0 * 2.f : 0.f;
  t1v = tf_keep(k0, k1, ridx + 1u) ? t1v * 2.f : 0.f;
  tls[(g << 6) + c0] = t0;
  tls[(g << 6) + c0 + 1] = t1v;
  __builtin_amdgcn_wave_barrier();
  // a16[l] = dinv[j] * sum_c t[c] * W3[c][l] — ascending-c == gemm_n64_k32
  float a = 0.f;
#pragma unroll
  for (int c = 0; c < 64; ++c) {
    a = fmaf(tls[(g << 6) + c], W3s[c * 32 + l], a);
  }
  if (j < n) {
    __builtin_nontemporal_store((half_t)(a * dj), &outh[(size_t)j * 32 + l]);
  }
}

// ---------------------------------------------------------------------------
extern "C" void kernel_launch(void* const* d_in, const int* in_sizes, int n_in,
                              void* d_out, int out_size, void* d_ws, size_t ws_size,
                              hipStream_t stream) {
  const float* x  = (const float*)d_in[0];
  const int*   ei = (const int*)d_in[1];
  const float* W1 = (const float*)d_in[2];
  const float* b1 = (const float*)d_in[3];
  const float* W2 = (const float*)d_in[4];
  const float* b2 = (const float*)d_in[5];
  const float* W3 = (const float*)d_in[6];
  const float* b3 = (const float*)d_in[7];
  float* out = (float*)d_out;

  const int n = in_sizes[0] / 64;
  const int E = in_sizes[1] / 2;
  const int* src = ei;
  const int* dst = ei + E;

  char* ws = (char*)d_ws;
  size_t off = 0;
  auto alloc = [&](size_t bytes) {
    void* p = ws + off;
    off = (off + bytes + 255) & ~(size_t)255;
    return p;
  };
  const int NB   = (n + 127) >> 7;
  const int NBLK = (E + CHUNK - 1) / CHUNK;

  half_t*   A16   = (half_t*)alloc((size_t)n * 32 * 2); // fp16 table (layers 1,3)
  half_t*   B16   = (half_t*)alloc((size_t)n * 32 * 2); // fp16 table (layer 2)
  float*    dinv  = (float*)alloc((size_t)n * 4);
  uint32_t* rowp  = (uint32_t*)alloc((size_t)(n + 1) * 4);
  uint32_t* esrc  = (uint32_t*)alloc((size_t)E * 4);
  uint32_t* gbcnt = (uint32_t*)alloc(1024 * 4);
  uint32_t* bbase = (uint32_t*)alloc(1024 * 4);
  uint32_t* staging = (uint32_t*)alloc((size_t)NBLK * CHUNK * 4);
  uint32_t* tbl     = (uint32_t*)alloc((size_t)NBLK * NB * 4);
  (void)ws_size; (void)n_in; (void)out_size;

  uint32_t k1a, k1b, k2a, k2b;
  tf2x32(0u, 42u, 0u, 0u, k1a, k1b);
  tf2x32(0u, 42u, 0u, 1u, k2a, k2b);

  const int nv   = n * 32;
  const int gV   = (nv + 255) / 256;
  const int gG1  = (n + 31) / 32;
  dim3 blk(256);

  // ---- CSR build (R3-proven) ----
  zero1024<<<1, dim3(1024), 0, stream>>>(gbcnt);
  k4_binhist<<<NBLK, dim3(1024), 0, stream>>>(src, dst, tbl, gbcnt, staging, E, NB);
  k3_bscan<<<1, dim3(1024), 0, stream>>>(gbcnt, bbase, NB);
  k5_fin<<<NB, dim3(1024), 0, stream>>>(staging, tbl, bbase, rowp, dinv, esrc, n, E, NBLK, NB);

  // ---- layer 1: A16 = fp16(dinv*(x@W1)); gather -> B16 (fp16) ----
  gemm_n64_k32<<<gG1, blk, 0, stream>>>(x, W1, dinv, A16, n);
  gather_fin<<<gV, blk, 0, stream>>>(A16, rowp, esrc, dinv, b1, nullptr, B16, n, 3, k1a, k1b, 1.0f);

  // ---- layers 2+3a fused: gather(B16) -> @W2,celu,drop -> @W3,xdinv -> A16 ----
  gather_gemm2<<<gV, blk, 0, stream>>>(B16, rowp, esrc, dinv, W2, b2, W3, A16, n, k2a, k2b);

  // ---- layer 3b: gather(A16) -> celu(+b3) -> out (fp32) ----
  gather_fin<<<gV, blk, 0, stream>>>(A16, rowp, esrc, dinv, b3, out, nullptr, n, 1, 0u, 0u, 1.0f);
}